// Round 3
// baseline (184.996 us; speedup 1.0000x reference)
//
#include <hip/hip_runtime.h>

#define BB 4
#define NN 4096
#define CC 128
#define NROWS (BB * NN)   // 16384 rows per tensor

// workspace layout (float offsets)
#define QN_OFF  0                              // |q| per row (16384)
#define KS_OFF  (QN_OFF + NROWS)               // B x 128  (sum of khat rows)
#define MT_OFF  (KS_OFF + BB * CC)             // B x 128 x 128  M^T (M = M0 W^T + Ksum b^T)
#define M2_OFF  (MT_OFF + BB * CC * CC)        // B x 128 x 128  M2 = W^T M, natural [f][e]
#define MB_OFF  (M2_OFF + BB * CC * CC)        // B x 128   mb = b @ M
#define KW_OFF  (MB_OFF + BB * CC)             // B x 128   kw = W^T Ksum
#define BKS_OFF (KW_OFF + BB * CC)             // B         bks = b . Ksum
#define PP_OFF  (BKS_OFF + BB)                 // 256 x 16384 partial M0s
#define KP_OFF  (PP_OFF + 256 * CC * CC)       // 256 x 128 partial ksums

// ---------------------------------------------------------------------------
// Kernel 1: fused projection + partial-M build.
// Blocks 0..255   (q): project 64 rows, store row norms only.
// Blocks 256..511 (k): project + normalize 64 rows, then REUSE the W LDS
//   buffer (dead after the proj loop) to hold khat(32KB)+v(32KB) tiles and
//   accumulate the 64-row partial M0 = khat^T @ v_node slice + partial ksum.
// ---------------------------------------------------------------------------
__global__ __launch_bounds__(256, 2) void projpb_kernel(
    const float* __restrict__ q_node, const float* __restrict__ k_node,
    const float* __restrict__ v_node, const float* __restrict__ W,
    const float* __restrict__ bias, float* __restrict__ ws)
{
    __shared__ float S[CC * CC];    // phase 1: swizzled W^T; phase 2: khat|v tiles
    __shared__ float4 red[256];     // ksum reduction
    const int tid = threadIdx.x;

    for (int e = tid; e < CC * CC; e += 256) {
        int d = e >> 7, c = e & 127;
        S[(c << 7) + ((((d >> 2) ^ (c & 31)) << 2) | (d & 3))] = W[e];
    }

    const int blk    = blockIdx.x;        // 0..511
    const int tensor = blk >> 8;          // 0:q 1:k
    const int rb     = blk & 255;
    const float* X = tensor ? k_node : q_node;

    const int dg = tid & 31;              // 4 output cols
    const int rg = tid >> 5;              // 8 row-groups x 8 rows
    const int row0 = rb * 64 + rg * 8;

    float4 bias4 = ((const float4*)bias)[dg];
    float4 acc[8];
#pragma unroll
    for (int i = 0; i < 8; i++) acc[i] = bias4;

    __syncthreads();

    const float4* Xv = (const float4*)(X + (size_t)row0 * CC);

    for (int c = 0; c < CC; c += 4) {
        const int c4 = c >> 2;
        float4 w0 = ((const float4*)S)[((c + 0) << 5) + (dg ^ ((c + 0) & 31))];
        float4 w1 = ((const float4*)S)[((c + 1) << 5) + (dg ^ ((c + 1) & 31))];
        float4 w2 = ((const float4*)S)[((c + 2) << 5) + (dg ^ ((c + 2) & 31))];
        float4 w3 = ((const float4*)S)[((c + 3) << 5) + (dg ^ ((c + 3) & 31))];
#pragma unroll
        for (int i = 0; i < 8; i++) {
            float4 x = Xv[i * 32 + c4];
            acc[i].x += x.x * w0.x + x.y * w1.x + x.z * w2.x + x.w * w3.x;
            acc[i].y += x.x * w0.y + x.y * w1.y + x.z * w2.y + x.w * w3.y;
            acc[i].z += x.x * w0.z + x.y * w1.z + x.z * w2.z + x.w * w3.z;
            acc[i].w += x.x * w0.w + x.y * w1.w + x.z * w2.w + x.w * w3.w;
        }
    }

    if (tensor == 0) {
        // q path: norms only
#pragma unroll
        for (int i = 0; i < 8; i++) {
            float ss = acc[i].x * acc[i].x + acc[i].y * acc[i].y
                     + acc[i].z * acc[i].z + acc[i].w * acc[i].w;
#pragma unroll
            for (int off = 16; off > 0; off >>= 1) ss += __shfl_xor(ss, off, 32);
            if (dg == 0) ws[QN_OFF + row0 + i] = sqrtf(ss);
        }
        return;
    }

    // k path: normalize in registers, then rebuild LDS as khat|v tiles
    __syncthreads();   // everyone done reading W from S before overwrite

    float* Khs = S;               // 64 x 128 floats (32 KB)
    float* Vs  = S + 64 * CC / 2 * 2;  // placeholder, set below
    Vs = S + 8192;                // 64 x 128 floats (32 KB)

#pragma unroll
    for (int i = 0; i < 8; i++) {
        float ss = acc[i].x * acc[i].x + acc[i].y * acc[i].y
                 + acc[i].z * acc[i].z + acc[i].w * acc[i].w;
#pragma unroll
        for (int off = 16; off > 0; off >>= 1) ss += __shfl_xor(ss, off, 32);
        float inv = 1.0f / sqrtf(ss);
        float4 o = acc[i];
        o.x *= inv; o.y *= inv; o.z *= inv; o.w *= inv;
        ((float4*)(Khs + (rg * 8 + i) * CC))[dg] = o;
    }

    // load v tile (64 rows starting at rb*64)
    const int c4 = tid & 31, nr = tid >> 5;
    const float* Vp = v_node + (size_t)rb * 64 * CC;
#pragma unroll
    for (int i = 0; i < 8; i++) {
        int n = nr + i * 8;
        ((float4*)(Vs + n * CC))[c4] = ((const float4*)(Vp + (size_t)n * CC))[c4];
    }
    __syncthreads();

    // partial ksum from the khat tile (each thread sums its 8 loader-rows)
    float4 ksum4 = make_float4(0.f, 0.f, 0.f, 0.f);
#pragma unroll
    for (int i = 0; i < 8; i++) {
        int n = nr + i * 8;
        float4 kv = ((const float4*)(Khs + n * CC))[c4];
        ksum4.x += kv.x; ksum4.y += kv.y; ksum4.z += kv.z; ksum4.w += kv.w;
    }

    // 8x8 register-tile outer-product accumulation over 64 rows
    const int dg2 = tid & 15, cg = tid >> 4;
    float a2[8][8];
#pragma unroll
    for (int i = 0; i < 8; i++)
#pragma unroll
        for (int j = 0; j < 8; j++) a2[i][j] = 0.f;

    for (int n = 0; n < 64; n++) {
        float4 ka = *(const float4*)(Khs + n * CC + 4 * cg);
        float4 kb = *(const float4*)(Khs + n * CC + 64 + 4 * cg);
        float4 va = *(const float4*)(Vs + n * CC + 4 * dg2);
        float4 vb = *(const float4*)(Vs + n * CC + 64 + 4 * dg2);
        float kc[8] = {ka.x, ka.y, ka.z, ka.w, kb.x, kb.y, kb.z, kb.w};
        float vd[8] = {va.x, va.y, va.z, va.w, vb.x, vb.y, vb.z, vb.w};
#pragma unroll
        for (int i = 0; i < 8; i++)
#pragma unroll
            for (int j = 0; j < 8; j++) a2[i][j] += kc[i] * vd[j];
    }

    float* pp = ws + PP_OFF + (size_t)rb * (CC * CC);
#pragma unroll
    for (int i = 0; i < 8; i++) {
        int c = 4 * cg + (i & 3) + (i >> 2) * 64;
        *(float4*)(pp + c * CC + 4 * dg2) =
            make_float4(a2[i][0], a2[i][1], a2[i][2], a2[i][3]);
        *(float4*)(pp + c * CC + 64 + 4 * dg2) =
            make_float4(a2[i][4], a2[i][5], a2[i][6], a2[i][7]);
    }

    red[nr * 32 + c4] = ksum4;
    __syncthreads();
    if (tid < 32) {
        float4 sm = red[tid];
#pragma unroll
        for (int i = 1; i < 8; i++) {
            float4 t = red[i * 32 + tid];
            sm.x += t.x; sm.y += t.y; sm.z += t.z; sm.w += t.w;
        }
        ((float4*)(ws + KP_OFF + (size_t)rb * CC))[tid] = sm;
    }
}

// ---------------------------------------------------------------------------
// Kernel 2: fused partial-reduce + mgemm1.
// Grid (8, B). Each block sums the 64 partials for its 16 M0-rows into LDS,
// then computes Mt rows: M = M0 @ W^T + Ksum b^T, stored transposed Mt[e][c].
// ---------------------------------------------------------------------------
__global__ __launch_bounds__(256) void redgemm1_kernel(const float* __restrict__ W,
                                                       const float* __restrict__ bias,
                                                       float* __restrict__ ws)
{
    __shared__ float Wt[CC * CC];   // 64 KB swizzled
    __shared__ float Xl[16 * CC];   // 8 KB: this block's 16 M0 rows
    __shared__ float ksl[16];

    const int tid = threadIdx.x;
    const int b = blockIdx.y, rb = blockIdx.x;

    for (int e = tid; e < CC * CC; e += 256) {
        int d = e >> 7, c = e & 127;
        Wt[(c << 7) + ((((d >> 2) ^ (c & 31)) << 2) | (d & 3))] = W[e];
    }

    // sum 64 partials for rows rb*16 .. rb*16+15
    const float* ppb = ws + PP_OFF + (size_t)(b * 64) * (CC * CC) + (size_t)(rb * 16) * CC;
    for (int le = tid; le < 16 * CC; le += 256) {
        float a0 = 0.f, a1 = 0.f, a2 = 0.f, a3 = 0.f;
#pragma unroll
        for (int s = 0; s < 64; s += 4) {
            a0 += ppb[(size_t)(s + 0) * (CC * CC) + le];
            a1 += ppb[(size_t)(s + 1) * (CC * CC) + le];
            a2 += ppb[(size_t)(s + 2) * (CC * CC) + le];
            a3 += ppb[(size_t)(s + 3) * (CC * CC) + le];
        }
        Xl[le] = (a0 + a1) + (a2 + a3);
    }
    // local ksum slice for the bias fold
    if (tid < 16) {
        const float* kp = ws + KP_OFF + (size_t)(b * 64) * CC + rb * 16 + tid;
        float s0 = 0.f;
#pragma unroll
        for (int s = 0; s < 64; s++) s0 += kp[s * CC];
        ksl[tid] = s0;
    }
    // full Ksum for downstream kernels (one block per batch)
    if (rb == 0 && tid < CC) {
        const float* kp = ws + KP_OFF + (size_t)(b * 64) * CC + tid;
        float s0 = 0.f;
#pragma unroll
        for (int s = 0; s < 64; s++) s0 += kp[s * CC];
        ws[KS_OFF + b * CC + tid] = s0;
    }
    __syncthreads();

    const int dg = tid & 31, rg = tid >> 5;
    const float4* Xv = (const float4*)(Xl + (rg * 2) * CC);
    float4 acc[2] = {make_float4(0.f,0.f,0.f,0.f), make_float4(0.f,0.f,0.f,0.f)};

    for (int d = 0; d < CC; d += 4) {
        const int d4 = d >> 2;
        float4 w0 = ((const float4*)Wt)[((d + 0) << 5) + (dg ^ ((d + 0) & 31))];
        float4 w1 = ((const float4*)Wt)[((d + 1) << 5) + (dg ^ ((d + 1) & 31))];
        float4 w2 = ((const float4*)Wt)[((d + 2) << 5) + (dg ^ ((d + 2) & 31))];
        float4 w3 = ((const float4*)Wt)[((d + 3) << 5) + (dg ^ ((d + 3) & 31))];
#pragma unroll
        for (int k = 0; k < 2; k++) {
            float4 x = Xv[k * 32 + d4];
            acc[k].x += x.x * w0.x + x.y * w1.x + x.z * w2.x + x.w * w3.x;
            acc[k].y += x.x * w0.y + x.y * w1.y + x.z * w2.y + x.w * w3.y;
            acc[k].z += x.x * w0.z + x.y * w1.z + x.z * w2.z + x.w * w3.z;
            acc[k].w += x.x * w0.w + x.y * w1.w + x.z * w2.w + x.w * w3.w;
        }
    }

    float4 b4 = ((const float4*)bias)[dg];
    float* Mt = ws + MT_OFF + (size_t)b * CC * CC;
    const int c0 = rb * 16 + rg * 2;
#pragma unroll
    for (int k = 0; k < 2; k++) {
        float ksc = ksl[rg * 2 + k];
        acc[k].x += ksc * b4.x; acc[k].y += ksc * b4.y;
        acc[k].z += ksc * b4.z; acc[k].w += ksc * b4.w;
        Mt[(4 * dg + 0) * CC + c0 + k] = acc[k].x;
        Mt[(4 * dg + 1) * CC + c0 + k] = acc[k].y;
        Mt[(4 * dg + 2) * CC + c0 + k] = acc[k].z;
        Mt[(4 * dg + 3) * CC + c0 + k] = acc[k].w;
    }
}

// ---------------------------------------------------------------------------
// Kernel 3: M2[f][e] = sum_c W[c][f] M[c][e] (from Mt rows), plus
// mb = b@M, kw = W^T Ksum, bks = b.Ksum.
// ---------------------------------------------------------------------------
__global__ __launch_bounds__(256) void mgemm2_kernel(const float* __restrict__ W,
                                                     const float* __restrict__ bias,
                                                     float* __restrict__ ws)
{
    __shared__ float Wn[CC * CC];   // W[c][f] swizzled in f
    const int tid = threadIdx.x;
    for (int e = tid; e < CC * CC; e += 256) {
        int c = e >> 7, f = e & 127;
        Wn[(c << 7) + ((((f >> 2) ^ (c & 31)) << 2) | (f & 3))] = W[e];
    }
    const int b = blockIdx.y, rb = blockIdx.x;
    const int dg = tid & 31, rg = tid >> 5;
    const int e0 = rb * 16 + rg * 2;
    const float4* Xv = (const float4*)(ws + MT_OFF + ((size_t)b * CC + e0) * CC);
    const float4* Ks4 = (const float4*)(ws + KS_OFF + b * CC);
    const float4* Bi4 = (const float4*)bias;

    float4 acc[2] = {make_float4(0.f,0.f,0.f,0.f), make_float4(0.f,0.f,0.f,0.f)};
    float macc[2] = {0.f, 0.f};
    float4 kw4 = make_float4(0.f, 0.f, 0.f, 0.f);
    __syncthreads();

    for (int c = 0; c < CC; c += 4) {
        const int c4 = c >> 2;
        float4 w0 = ((const float4*)Wn)[((c + 0) << 5) + (dg ^ ((c + 0) & 31))];
        float4 w1 = ((const float4*)Wn)[((c + 1) << 5) + (dg ^ ((c + 1) & 31))];
        float4 w2 = ((const float4*)Wn)[((c + 2) << 5) + (dg ^ ((c + 2) & 31))];
        float4 w3 = ((const float4*)Wn)[((c + 3) << 5) + (dg ^ ((c + 3) & 31))];
        float4 ks = Ks4[c4];
        float4 bb = Bi4[c4];
        kw4.x += ks.x * w0.x + ks.y * w1.x + ks.z * w2.x + ks.w * w3.x;
        kw4.y += ks.x * w0.y + ks.y * w1.y + ks.z * w2.y + ks.w * w3.y;
        kw4.z += ks.x * w0.z + ks.y * w1.z + ks.z * w2.z + ks.w * w3.z;
        kw4.w += ks.x * w0.w + ks.y * w1.w + ks.z * w2.w + ks.w * w3.w;
#pragma unroll
        for (int k = 0; k < 2; k++) {
            float4 x = Xv[k * 32 + c4];
            acc[k].x += x.x * w0.x + x.y * w1.x + x.z * w2.x + x.w * w3.x;
            acc[k].y += x.x * w0.y + x.y * w1.y + x.z * w2.y + x.w * w3.y;
            acc[k].z += x.x * w0.z + x.y * w1.z + x.z * w2.z + x.w * w3.z;
            acc[k].w += x.x * w0.w + x.y * w1.w + x.z * w2.w + x.w * w3.w;
            macc[k] += x.x * bb.x + x.y * bb.y + x.z * bb.z + x.w * bb.w;
        }
    }

    float* M2 = ws + M2_OFF + (size_t)b * CC * CC;
#pragma unroll
    for (int k = 0; k < 2; k++) {
        M2[(4 * dg + 0) * CC + e0 + k] = acc[k].x;
        M2[(4 * dg + 1) * CC + e0 + k] = acc[k].y;
        M2[(4 * dg + 2) * CC + e0 + k] = acc[k].z;
        M2[(4 * dg + 3) * CC + e0 + k] = acc[k].w;
        if (dg == 0) ws[MB_OFF + b * CC + e0 + k] = macc[k];
    }
    if (rb == 0 && rg == 0)
        ((float4*)(ws + KW_OFF + b * CC))[dg] = kw4;
    if (rb == 0 && tid == 0) {
        float s = 0.f;
        for (int c = 0; c < CC; c++) s += bias[c] * ws[KS_OFF + b * CC + c];
        ws[BKS_OFF + b] = s;
    }
}

// ---------------------------------------------------------------------------
// Kernel 4: out[b,r,:] = (q_node[b,r,:] @ M2 + mb) / (q_node.kw + bks + 1e-8|q|)
// ---------------------------------------------------------------------------
__global__ __launch_bounds__(256, 2) void out_kernel(const float* __restrict__ q_node,
                                                     const float* __restrict__ ws,
                                                     float* __restrict__ out)
{
    __shared__ float Ml[CC * CC];

    const int blk = blockIdx.x;     // 0..511
    const int b = blk >> 7;
    const int r0 = (blk & 127) * 32;
    const float* M2 = ws + M2_OFF + (size_t)b * CC * CC;
    const int tid = threadIdx.x;

    for (int e = tid; e < CC * CC / 4; e += 256)
        ((float4*)Ml)[e] = ((const float4*)M2)[e];

    const float4* Kw4 = (const float4*)(ws + KW_OFF + b * CC);
    const float4* Mb4 = (const float4*)(ws + MB_OFF + b * CC);
    const float bks = ws[BKS_OFF + b];
    const int dg = tid & 31, rg = tid >> 5;
    const int row = r0 + rg * 4;
    const float4* Qv = (const float4*)(q_node + ((size_t)b * NN + row) * CC);

    float4 acc[4];
    float s[4];
    float4 mb4 = Mb4[dg];
#pragma unroll
    for (int i = 0; i < 4; i++) { acc[i] = mb4; s[i] = bks; }

    __syncthreads();

    for (int f = 0; f < CC; f += 4) {
        const int f4 = f >> 2;
        float4 m0 = ((const float4*)Ml)[((f + 0) << 5) + dg];
        float4 m1 = ((const float4*)Ml)[((f + 1) << 5) + dg];
        float4 m2 = ((const float4*)Ml)[((f + 2) << 5) + dg];
        float4 m3 = ((const float4*)Ml)[((f + 3) << 5) + dg];
        float4 kw = Kw4[f4];
#pragma unroll
        for (int i = 0; i < 4; i++) {
            float4 x = Qv[i * 32 + f4];
            acc[i].x += x.x * m0.x + x.y * m1.x + x.z * m2.x + x.w * m3.x;
            acc[i].y += x.x * m0.y + x.y * m1.y + x.z * m2.y + x.w * m3.y;
            acc[i].z += x.x * m0.z + x.y * m1.z + x.z * m2.z + x.w * m3.z;
            acc[i].w += x.x * m0.w + x.y * m1.w + x.z * m2.w + x.w * m3.w;
            s[i] += x.x * kw.x + x.y * kw.y + x.z * kw.z + x.w * kw.w;
        }
    }

    float* op = out + ((size_t)b * NN + row) * CC;
    const float* qn = ws + QN_OFF + (size_t)b * NN + row;
#pragma unroll
    for (int i = 0; i < 4; i++) {
        float inv = 1.0f / (s[i] + 1e-8f * qn[i]);
        float4 o = acc[i];
        o.x *= inv; o.y *= inv; o.z *= inv; o.w *= inv;
        ((float4*)(op + (size_t)i * CC))[dg] = o;
    }
}

// ---------------------------------------------------------------------------
extern "C" void kernel_launch(void* const* d_in, const int* in_sizes, int n_in,
                              void* d_out, int out_size, void* d_ws, size_t ws_size,
                              hipStream_t stream)
{
    const float* q_node = (const float*)d_in[0];
    const float* k_node = (const float*)d_in[1];
    const float* v_node = (const float*)d_in[2];
    const float* W      = (const float*)d_in[3];
    const float* bias   = (const float*)d_in[4];
    float* out = (float*)d_out;
    float* ws  = (float*)d_ws;

    projpb_kernel<<<512, 256, 0, stream>>>(q_node, k_node, v_node, W, bias, ws);
    redgemm1_kernel<<<dim3(8, BB), 256, 0, stream>>>(W, bias, ws);
    mgemm2_kernel<<<dim3(8, BB), 256, 0, stream>>>(W, bias, ws);
    out_kernel<<<512, 256, 0, stream>>>(q_node, ws, out);
}

// Round 4
// 150.779 us; speedup vs baseline: 1.2269x; 1.2269x over previous
//
#include <hip/hip_runtime.h>

#define BB 4
#define NN 4096
#define CC 128
#define NROWS (BB * NN)   // 16384 rows per tensor

// workspace layout (float offsets)
#define QN_OFF  0                              // |q| per row (16384)
#define M0_OFF  (QN_OFF + NROWS)               // B x 128 x 128  (Khat^T @ v_node)
#define KS_OFF  (M0_OFF + BB * CC * CC)        // B x 128  (sum of khat rows)
#define MT_OFF  (KS_OFF + BB * CC)             // B x 128 x 128  M^T (M = M0 W^T + Ksum b^T)
#define M2_OFF  (MT_OFF + BB * CC * CC)        // B x 128 x 128  M2 = W^T M, natural [f][e]
#define MB_OFF  (M2_OFF + BB * CC * CC)        // B x 128   mb = b @ M
#define KW_OFF  (MB_OFF + BB * CC)             // B x 128   kw = W^T Ksum
#define BKS_OFF (KW_OFF + BB * CC)             // B         bks = b . Ksum
#define PP_OFF  (BKS_OFF + BB)                 // 256 x 16384 partial M0s
#define KP_OFF  (PP_OFF + 256 * CC * CC)       // 256 x 128 partial ksums

// ---------------------------------------------------------------------------
// Kernel 1: fused projection + partial-M build (validated in R3).
// Blocks 0..255   (q): project 64 rows, store row norms only.
// Blocks 256..511 (k): project + normalize 64 rows, reuse dead W-LDS for
//   khat|v tiles, accumulate 64-row partial M0 + partial ksum.
// ---------------------------------------------------------------------------
__global__ __launch_bounds__(256, 2) void projpb_kernel(
    const float* __restrict__ q_node, const float* __restrict__ k_node,
    const float* __restrict__ v_node, const float* __restrict__ W,
    const float* __restrict__ bias, float* __restrict__ ws)
{
    __shared__ float S[CC * CC];    // phase 1: swizzled W^T; phase 2: khat|v tiles
    __shared__ float4 red[256];
    const int tid = threadIdx.x;

    for (int e = tid; e < CC * CC; e += 256) {
        int d = e >> 7, c = e & 127;
        S[(c << 7) + ((((d >> 2) ^ (c & 31)) << 2) | (d & 3))] = W[e];
    }

    const int blk    = blockIdx.x;        // 0..511
    const int tensor = blk >> 8;          // 0:q 1:k
    const int rb     = blk & 255;
    const float* X = tensor ? k_node : q_node;

    const int dg = tid & 31;
    const int rg = tid >> 5;
    const int row0 = rb * 64 + rg * 8;

    float4 bias4 = ((const float4*)bias)[dg];
    float4 acc[8];
#pragma unroll
    for (int i = 0; i < 8; i++) acc[i] = bias4;

    __syncthreads();

    const float4* Xv = (const float4*)(X + (size_t)row0 * CC);

    for (int c = 0; c < CC; c += 4) {
        const int c4 = c >> 2;
        float4 w0 = ((const float4*)S)[((c + 0) << 5) + (dg ^ ((c + 0) & 31))];
        float4 w1 = ((const float4*)S)[((c + 1) << 5) + (dg ^ ((c + 1) & 31))];
        float4 w2 = ((const float4*)S)[((c + 2) << 5) + (dg ^ ((c + 2) & 31))];
        float4 w3 = ((const float4*)S)[((c + 3) << 5) + (dg ^ ((c + 3) & 31))];
#pragma unroll
        for (int i = 0; i < 8; i++) {
            float4 x = Xv[i * 32 + c4];
            acc[i].x += x.x * w0.x + x.y * w1.x + x.z * w2.x + x.w * w3.x;
            acc[i].y += x.x * w0.y + x.y * w1.y + x.z * w2.y + x.w * w3.y;
            acc[i].z += x.x * w0.z + x.y * w1.z + x.z * w2.z + x.w * w3.z;
            acc[i].w += x.x * w0.w + x.y * w1.w + x.z * w2.w + x.w * w3.w;
        }
    }

    if (tensor == 0) {
#pragma unroll
        for (int i = 0; i < 8; i++) {
            float ss = acc[i].x * acc[i].x + acc[i].y * acc[i].y
                     + acc[i].z * acc[i].z + acc[i].w * acc[i].w;
#pragma unroll
            for (int off = 16; off > 0; off >>= 1) ss += __shfl_xor(ss, off, 32);
            if (dg == 0) ws[QN_OFF + row0 + i] = sqrtf(ss);
        }
        return;
    }

    __syncthreads();   // everyone done reading W before overwrite

    float* Khs = S;            // 64 x 128 (32 KB)
    float* Vs  = S + 8192;     // 64 x 128 (32 KB)

#pragma unroll
    for (int i = 0; i < 8; i++) {
        float ss = acc[i].x * acc[i].x + acc[i].y * acc[i].y
                 + acc[i].z * acc[i].z + acc[i].w * acc[i].w;
#pragma unroll
        for (int off = 16; off > 0; off >>= 1) ss += __shfl_xor(ss, off, 32);
        float inv = 1.0f / sqrtf(ss);
        float4 o = acc[i];
        o.x *= inv; o.y *= inv; o.z *= inv; o.w *= inv;
        ((float4*)(Khs + (rg * 8 + i) * CC))[dg] = o;
    }

    const int c4 = tid & 31, nr = tid >> 5;
    const float* Vp = v_node + (size_t)rb * 64 * CC;
#pragma unroll
    for (int i = 0; i < 8; i++) {
        int n = nr + i * 8;
        ((float4*)(Vs + n * CC))[c4] = ((const float4*)(Vp + (size_t)n * CC))[c4];
    }
    __syncthreads();

    float4 ksum4 = make_float4(0.f, 0.f, 0.f, 0.f);
#pragma unroll
    for (int i = 0; i < 8; i++) {
        int n = nr + i * 8;
        float4 kv = ((const float4*)(Khs + n * CC))[c4];
        ksum4.x += kv.x; ksum4.y += kv.y; ksum4.z += kv.z; ksum4.w += kv.w;
    }

    const int dg2 = tid & 15, cg = tid >> 4;
    float a2[8][8];
#pragma unroll
    for (int i = 0; i < 8; i++)
#pragma unroll
        for (int j = 0; j < 8; j++) a2[i][j] = 0.f;

    for (int n = 0; n < 64; n++) {
        float4 ka = *(const float4*)(Khs + n * CC + 4 * cg);
        float4 kb = *(const float4*)(Khs + n * CC + 64 + 4 * cg);
        float4 va = *(const float4*)(Vs + n * CC + 4 * dg2);
        float4 vb = *(const float4*)(Vs + n * CC + 64 + 4 * dg2);
        float kc[8] = {ka.x, ka.y, ka.z, ka.w, kb.x, kb.y, kb.z, kb.w};
        float vd[8] = {va.x, va.y, va.z, va.w, vb.x, vb.y, vb.z, vb.w};
#pragma unroll
        for (int i = 0; i < 8; i++)
#pragma unroll
            for (int j = 0; j < 8; j++) a2[i][j] += kc[i] * vd[j];
    }

    float* pp = ws + PP_OFF + (size_t)rb * (CC * CC);
#pragma unroll
    for (int i = 0; i < 8; i++) {
        int c = 4 * cg + (i & 3) + (i >> 2) * 64;
        *(float4*)(pp + c * CC + 4 * dg2) =
            make_float4(a2[i][0], a2[i][1], a2[i][2], a2[i][3]);
        *(float4*)(pp + c * CC + 64 + 4 * dg2) =
            make_float4(a2[i][4], a2[i][5], a2[i][6], a2[i][7]);
    }

    red[nr * 32 + c4] = ksum4;
    __syncthreads();
    if (tid < 32) {
        float4 sm = red[tid];
#pragma unroll
        for (int i = 1; i < 8; i++) {
            float4 t = red[i * 32 + tid];
            sm.x += t.x; sm.y += t.y; sm.z += t.z; sm.w += t.w;
        }
        ((float4*)(ws + KP_OFF + (size_t)rb * CC))[tid] = sm;
    }
}

// ---------------------------------------------------------------------------
// Kernel 2: reduce 64 partials -> M0[b], Ksum[b]. 256 blocks (full machine).
// ---------------------------------------------------------------------------
__global__ __launch_bounds__(256) void reduce_kernel(float* __restrict__ ws)
{
    const int b = blockIdx.y, x = blockIdx.x, tid = threadIdx.x;
    const int e = (x << 8) + tid;                      // 0..16383
    const float* pp = ws + PP_OFF + (size_t)(b * 64) * (CC * CC) + e;
    float a0 = 0.f, a1 = 0.f, a2 = 0.f, a3 = 0.f;
#pragma unroll
    for (int s = 0; s < 64; s += 4) {
        a0 += pp[(size_t)(s + 0) * (CC * CC)];
        a1 += pp[(size_t)(s + 1) * (CC * CC)];
        a2 += pp[(size_t)(s + 2) * (CC * CC)];
        a3 += pp[(size_t)(s + 3) * (CC * CC)];
    }
    ws[M0_OFF + b * CC * CC + e] = (a0 + a1) + (a2 + a3);

    if (x == 0 && tid < CC) {
        const float* kp = ws + KP_OFF + (size_t)(b * 64) * CC + tid;
        float k0 = 0.f;
#pragma unroll
        for (int s = 0; s < 64; s++) k0 += kp[s * CC];
        ws[KS_OFF + b * CC + tid] = k0;
    }
}

// ---------------------------------------------------------------------------
// Kernel 3: M = M0 @ W^T + Ksum b^T, stored TRANSPOSED as Mt[e][c].
// ---------------------------------------------------------------------------
__global__ __launch_bounds__(256) void mgemm1_kernel(const float* __restrict__ W,
                                                     const float* __restrict__ bias,
                                                     float* __restrict__ ws)
{
    __shared__ float Wt[CC * CC];
    const int tid = threadIdx.x;
    for (int e = tid; e < CC * CC; e += 256) {
        int d = e >> 7, c = e & 127;
        Wt[(c << 7) + ((((d >> 2) ^ (c & 31)) << 2) | (d & 3))] = W[e];
    }
    const int b = blockIdx.y, rb = blockIdx.x;
    const int dg = tid & 31, rg = tid >> 5;
    const int c0 = rb * 16 + rg * 2;
    const float4* Xv = (const float4*)(ws + M0_OFF + ((size_t)b * CC + c0) * CC);
    float4 acc[2] = {make_float4(0.f,0.f,0.f,0.f), make_float4(0.f,0.f,0.f,0.f)};
    __syncthreads();

    for (int d = 0; d < CC; d += 4) {
        const int d4 = d >> 2;
        float4 w0 = ((const float4*)Wt)[((d + 0) << 5) + (dg ^ ((d + 0) & 31))];
        float4 w1 = ((const float4*)Wt)[((d + 1) << 5) + (dg ^ ((d + 1) & 31))];
        float4 w2 = ((const float4*)Wt)[((d + 2) << 5) + (dg ^ ((d + 2) & 31))];
        float4 w3 = ((const float4*)Wt)[((d + 3) << 5) + (dg ^ ((d + 3) & 31))];
#pragma unroll
        for (int k = 0; k < 2; k++) {
            float4 x = Xv[k * 32 + d4];
            acc[k].x += x.x * w0.x + x.y * w1.x + x.z * w2.x + x.w * w3.x;
            acc[k].y += x.x * w0.y + x.y * w1.y + x.z * w2.y + x.w * w3.y;
            acc[k].z += x.x * w0.z + x.y * w1.z + x.z * w2.z + x.w * w3.z;
            acc[k].w += x.x * w0.w + x.y * w1.w + x.z * w2.w + x.w * w3.w;
        }
    }

    float4 b4 = ((const float4*)bias)[dg];
    float* Mt = ws + MT_OFF + (size_t)b * CC * CC;
#pragma unroll
    for (int k = 0; k < 2; k++) {
        float ksc = ws[KS_OFF + b * CC + c0 + k];
        acc[k].x += ksc * b4.x; acc[k].y += ksc * b4.y;
        acc[k].z += ksc * b4.z; acc[k].w += ksc * b4.w;
        Mt[(4 * dg + 0) * CC + c0 + k] = acc[k].x;
        Mt[(4 * dg + 1) * CC + c0 + k] = acc[k].y;
        Mt[(4 * dg + 2) * CC + c0 + k] = acc[k].z;
        Mt[(4 * dg + 3) * CC + c0 + k] = acc[k].w;
    }
}

// ---------------------------------------------------------------------------
// Kernel 4: M2[f][e] = sum_c W[c][f] M[c][e] (from Mt rows), plus
// mb = b@M, kw = W^T Ksum, bks = b.Ksum.
// ---------------------------------------------------------------------------
__global__ __launch_bounds__(256) void mgemm2_kernel(const float* __restrict__ W,
                                                     const float* __restrict__ bias,
                                                     float* __restrict__ ws)
{
    __shared__ float Wn[CC * CC];   // W[c][f] swizzled in f
    const int tid = threadIdx.x;
    for (int e = tid; e < CC * CC; e += 256) {
        int c = e >> 7, f = e & 127;
        Wn[(c << 7) + ((((f >> 2) ^ (c & 31)) << 2) | (f & 3))] = W[e];
    }
    const int b = blockIdx.y, rb = blockIdx.x;
    const int dg = tid & 31, rg = tid >> 5;
    const int e0 = rb * 16 + rg * 2;
    const float4* Xv = (const float4*)(ws + MT_OFF + ((size_t)b * CC + e0) * CC);
    const float4* Ks4 = (const float4*)(ws + KS_OFF + b * CC);
    const float4* Bi4 = (const float4*)bias;

    float4 acc[2] = {make_float4(0.f,0.f,0.f,0.f), make_float4(0.f,0.f,0.f,0.f)};
    float macc[2] = {0.f, 0.f};
    float4 kw4 = make_float4(0.f, 0.f, 0.f, 0.f);
    __syncthreads();

    for (int c = 0; c < CC; c += 4) {
        const int c4 = c >> 2;
        float4 w0 = ((const float4*)Wn)[((c + 0) << 5) + (dg ^ ((c + 0) & 31))];
        float4 w1 = ((const float4*)Wn)[((c + 1) << 5) + (dg ^ ((c + 1) & 31))];
        float4 w2 = ((const float4*)Wn)[((c + 2) << 5) + (dg ^ ((c + 2) & 31))];
        float4 w3 = ((const float4*)Wn)[((c + 3) << 5) + (dg ^ ((c + 3) & 31))];
        float4 ks = Ks4[c4];
        float4 bb = Bi4[c4];
        kw4.x += ks.x * w0.x + ks.y * w1.x + ks.z * w2.x + ks.w * w3.x;
        kw4.y += ks.x * w0.y + ks.y * w1.y + ks.z * w2.y + ks.w * w3.y;
        kw4.z += ks.x * w0.z + ks.y * w1.z + ks.z * w2.z + ks.w * w3.z;
        kw4.w += ks.x * w0.w + ks.y * w1.w + ks.z * w2.w + ks.w * w3.w;
#pragma unroll
        for (int k = 0; k < 2; k++) {
            float4 x = Xv[k * 32 + c4];
            acc[k].x += x.x * w0.x + x.y * w1.x + x.z * w2.x + x.w * w3.x;
            acc[k].y += x.x * w0.y + x.y * w1.y + x.z * w2.y + x.w * w3.y;
            acc[k].z += x.x * w0.z + x.y * w1.z + x.z * w2.z + x.w * w3.z;
            acc[k].w += x.x * w0.w + x.y * w1.w + x.z * w2.w + x.w * w3.w;
            macc[k] += x.x * bb.x + x.y * bb.y + x.z * bb.z + x.w * bb.w;
        }
    }

    float* M2 = ws + M2_OFF + (size_t)b * CC * CC;
#pragma unroll
    for (int k = 0; k < 2; k++) {
        M2[(4 * dg + 0) * CC + e0 + k] = acc[k].x;
        M2[(4 * dg + 1) * CC + e0 + k] = acc[k].y;
        M2[(4 * dg + 2) * CC + e0 + k] = acc[k].z;
        M2[(4 * dg + 3) * CC + e0 + k] = acc[k].w;
        if (dg == 0) ws[MB_OFF + b * CC + e0 + k] = macc[k];
    }
    if (rb == 0 && rg == 0)
        ((float4*)(ws + KW_OFF + b * CC))[dg] = kw4;
    if (rb == 0 && tid == 0) {
        float s = 0.f;
        for (int c = 0; c < CC; c++) s += bias[c] * ws[KS_OFF + b * CC + c];
        ws[BKS_OFF + b] = s;
    }
}

// ---------------------------------------------------------------------------
// Kernel 5: out[b,r,:] = (q_node[b,r,:] @ M2 + mb) / (q_node.kw + bks + 1e-8|q|)
// ---------------------------------------------------------------------------
__global__ __launch_bounds__(256, 2) void out_kernel(const float* __restrict__ q_node,
                                                     const float* __restrict__ ws,
                                                     float* __restrict__ out)
{
    __shared__ float Ml[CC * CC];

    const int blk = blockIdx.x;     // 0..511
    const int b = blk >> 7;
    const int r0 = (blk & 127) * 32;
    const float* M2 = ws + M2_OFF + (size_t)b * CC * CC;
    const int tid = threadIdx.x;

    for (int e = tid; e < CC * CC / 4; e += 256)
        ((float4*)Ml)[e] = ((const float4*)M2)[e];

    const float4* Kw4 = (const float4*)(ws + KW_OFF + b * CC);
    const float4* Mb4 = (const float4*)(ws + MB_OFF + b * CC);
    const float bks = ws[BKS_OFF + b];
    const int dg = tid & 31, rg = tid >> 5;
    const int row = r0 + rg * 4;
    const float4* Qv = (const float4*)(q_node + ((size_t)b * NN + row) * CC);

    float4 acc[4];
    float s[4];
    float4 mb4 = Mb4[dg];
#pragma unroll
    for (int i = 0; i < 4; i++) { acc[i] = mb4; s[i] = bks; }

    __syncthreads();

    for (int f = 0; f < CC; f += 4) {
        const int f4 = f >> 2;
        float4 m0 = ((const float4*)Ml)[((f + 0) << 5) + dg];
        float4 m1 = ((const float4*)Ml)[((f + 1) << 5) + dg];
        float4 m2 = ((const float4*)Ml)[((f + 2) << 5) + dg];
        float4 m3 = ((const float4*)Ml)[((f + 3) << 5) + dg];
        float4 kw = Kw4[f4];
#pragma unroll
        for (int i = 0; i < 4; i++) {
            float4 x = Qv[i * 32 + f4];
            acc[i].x += x.x * m0.x + x.y * m1.x + x.z * m2.x + x.w * m3.x;
            acc[i].y += x.x * m0.y + x.y * m1.y + x.z * m2.y + x.w * m3.y;
            acc[i].z += x.x * m0.z + x.y * m1.z + x.z * m2.z + x.w * m3.z;
            acc[i].w += x.x * m0.w + x.y * m1.w + x.z * m2.w + x.w * m3.w;
            s[i] += x.x * kw.x + x.y * kw.y + x.z * kw.z + x.w * kw.w;
        }
    }

    float* op = out + ((size_t)b * NN + row) * CC;
    const float* qn = ws + QN_OFF + (size_t)b * NN + row;
#pragma unroll
    for (int i = 0; i < 4; i++) {
        float inv = 1.0f / (s[i] + 1e-8f * qn[i]);
        float4 o = acc[i];
        o.x *= inv; o.y *= inv; o.z *= inv; o.w *= inv;
        ((float4*)(op + (size_t)i * CC))[dg] = o;
    }
}

// ---------------------------------------------------------------------------
extern "C" void kernel_launch(void* const* d_in, const int* in_sizes, int n_in,
                              void* d_out, int out_size, void* d_ws, size_t ws_size,
                              hipStream_t stream)
{
    const float* q_node = (const float*)d_in[0];
    const float* k_node = (const float*)d_in[1];
    const float* v_node = (const float*)d_in[2];
    const float* W      = (const float*)d_in[3];
    const float* bias   = (const float*)d_in[4];
    float* out = (float*)d_out;
    float* ws  = (float*)d_ws;

    projpb_kernel<<<512, 256, 0, stream>>>(q_node, k_node, v_node, W, bias, ws);
    reduce_kernel<<<dim3(64, BB), 256, 0, stream>>>(ws);
    mgemm1_kernel<<<dim3(8, BB), 256, 0, stream>>>(W, bias, ws);
    mgemm2_kernel<<<dim3(8, BB), 256, 0, stream>>>(W, bias, ws);
    out_kernel<<<512, 256, 0, stream>>>(q_node, ws, out);
}